// Round 3
// baseline (269.261 us; speedup 1.0000x reference)
//
#include <hip/hip_runtime.h>
#include <hip/hip_bf16.h>

#define NGRAPH 1024
#define NPG 128
#define NTOT (NGRAPH*NPG)
#define EPG 2048
#define ETOT (NTOT*16)
#define HD 64

typedef unsigned int uint;
typedef unsigned short ushort_t;
typedef __attribute__((ext_vector_type(8))) short s8v;
typedef __attribute__((ext_vector_type(4))) float f32x4;

#define MFMA16 __builtin_amdgcn_mfma_f32_16x16x32_bf16

__device__ __forceinline__ float lrelu(float x, float s){ return fmaxf(x, x*s); }
__device__ __forceinline__ float b2lo(uint u){ return __uint_as_float(u << 16); }
__device__ __forceinline__ float b2hi(uint u){ return __uint_as_float(u & 0xFFFF0000u); }
__device__ __forceinline__ uint pkbf(float a, float b){
  union { __hip_bfloat162 h; uint u; } t;
  t.h = __hip_bfloat162{__float2bfloat16(a), __float2bfloat16(b)};
  return t.u;
}
__device__ __forceinline__ ushort_t bfb(float v){
  __hip_bfloat16 h = __float2bfloat16(v);
  union { __hip_bfloat16 h; ushort_t u; } t; t.h = h; return t.u;
}
union U4S8 { uint4 u; s8v s; };
__device__ __forceinline__ s8v bcs8(uint4 u){ U4S8 t; t.u = u; return t.s; }

// DPP add: disabled/invalid source lanes contribute 0 (row_shr 1/2/4 -> sum at lane&7==7)
#define DPP_ADD(v, ctrl) ((v) + __int_as_float(__builtin_amdgcn_update_dpp(0, __float_as_int(v), (ctrl), 0xF, 0xF, false)))

// ROW32: bf16 rows of 64 (32 u32 pairs), octet-XOR swizzle
__device__ __forceinline__ int oswz(int r, int p){ return (r<<5) | ((((p>>2) ^ (r & 7))<<2) | (p & 3)); }
__device__ __forceinline__ int obase(int r, int oc){ return (r<<5) | (((oc) ^ (r & 7))<<2); }
// staging [64][32] u32, row-XOR column swizzle (conflict-free both sides)
__device__ __forceinline__ int sstg(int r, int c){ return (r<<5) | ((c ^ r) & 31); }

// LDS map (u32 units) -- 38,416 B total => 4 blocks/CU (all 1024 blocks co-resident)
#define O_F   0        // 4096: FEAT [128][32 pairs] bf16 ROW32: xl -> h -> Xw -> h' (in place)
#define O_W   4096     // 2048: WgT ROW32 [64][32] / GATv2 raw f32 logits [2048] / agg staging [64][32]
#define O_EV  6144     // 1024: edge exp values f16 [2048]
#define O_ED  7168     // 1024: edsd u16 [2048]
#define O_X   8192     // 512:  x f32 [128][4]
#define O_SOF 8704     // 129
#define O_SPO 8833     // 128
#define O_NMV 8961     // 128
#define O_SSE 9089     // 128
#define O_ALS 9217     // 128
#define O_ALD 9345     // 128 (+3 pad)
#define O_WAS 9476     // 64 (16B aligned)
#define O_WAD 9540     // 64
#define SM_SZ 9604     // 38,416 B

// gather 16 feats (quarter qf) of row (s) scaled by (a) into acc[16]
#define GF16(s, a) { \
    uint4 q0 = *(uint4*)&SM[O_F + obase((s), 2*qf+0)]; \
    uint4 q1 = *(uint4*)&SM[O_F + obase((s), 2*qf+1)]; \
    acc[0]  += (a)*b2lo(q0.x); acc[1]  += (a)*b2hi(q0.x); \
    acc[2]  += (a)*b2lo(q0.y); acc[3]  += (a)*b2hi(q0.y); \
    acc[4]  += (a)*b2lo(q0.z); acc[5]  += (a)*b2hi(q0.z); \
    acc[6]  += (a)*b2lo(q0.w); acc[7]  += (a)*b2hi(q0.w); \
    acc[8]  += (a)*b2lo(q1.x); acc[9]  += (a)*b2hi(q1.x); \
    acc[10] += (a)*b2lo(q1.y); acc[11] += (a)*b2hi(q1.y); \
    acc[12] += (a)*b2lo(q1.z); acc[13] += (a)*b2hi(q1.z); \
    acc[14] += (a)*b2lo(q1.w); acc[15] += (a)*b2hi(q1.w); }

__global__ __launch_bounds__(256)
__attribute__((amdgpu_waves_per_eu(4, 4)))
void gnn_fused(
    const float* __restrict__ x, const int* __restrict__ ei,
    const float* __restrict__ Wl, const float* __restrict__ bl,
    const float* __restrict__ Wr, const float* __restrict__ br,
    const float* __restrict__ att, const float* __restrict__ bv2,
    const float* __restrict__ Wg1, const float* __restrict__ as1,
    const float* __restrict__ ad1, const float* __restrict__ bg1,
    const float* __restrict__ Wg2, const float* __restrict__ as2,
    const float* __restrict__ ad2, const float* __restrict__ bg2,
    const float* __restrict__ lng, const float* __restrict__ lnb,
    uint* __restrict__ hout)
{
  __shared__ uint SM[SM_SZ];
  uint*      sXl  = SM + O_F;
  _Float16*  evh  = (_Float16*)(SM + O_EV);
  ushort_t*  edsd = (ushort_t*)(SM + O_ED);
  int*       soff = (int*)(SM + O_SOF);
  int*       spos = (int*)(SM + O_SPO);
  float*     nmv  = (float*)(SM + O_NMV);
  float*     sse  = (float*)(SM + O_SSE);
  float*     als  = (float*)(SM + O_ALS);
  float*     ald  = (float*)(SM + O_ALD);
  float*     was  = (float*)(SM + O_WAS);
  float*     wad  = (float*)(SM + O_WAD);
  ushort_t*  sH16 = (ushort_t*)(SM + O_F);
  ushort_t*  wg16 = (ushort_t*)(SM + O_W);
  float*     lgf  = (float*)(SM + O_W);
  uint*      stg  = SM + O_W;

  const int g    = blockIdx.x;
  const int tid  = threadIdx.x;
  const int lane = tid & 63;
  const int wv   = tid >> 6;
  const int lw   = lane & 15;      // MFMA: col/row low
  const int lq   = lane >> 4;      // MFMA: quad
  const int oc   = lane & 7;       // octet within 64-feat row
  const int ebase = g * EPG;

  // ---------------- CSR build ----------------
  if (tid < NPG) spos[tid] = 0;
  __syncthreads();
  for (int e = tid; e < EPG; e += 256)
    atomicAdd(&spos[ei[ETOT + ebase + e] - g*NPG], 1);
  __syncthreads();
  if (wv == 0) {
    int c0 = spos[lane], c1 = spos[lane + 64];
    #pragma unroll
    for (int o = 1; o < 64; o <<= 1) { int t = __shfl_up(c0, o); if (lane >= o) c0 += t; }
    #pragma unroll
    for (int o = 1; o < 64; o <<= 1) { int t = __shfl_up(c1, o); if (lane >= o) c1 += t; }
    int tot0 = __shfl(c0, 63);
    soff[lane + 1]  = c0;
    soff[lane + 65] = c1 + tot0;
    if (lane == 0) soff[0] = 0;
  }
  __syncthreads();
  if (tid < NPG) spos[tid] = soff[tid];
  __syncthreads();
  for (int e = tid; e < EPG; e += 256) {
    int s = ei[ebase + e] - g*NPG;
    int d = ei[ETOT + ebase + e] - g*NPG;
    int p = atomicAdd(&spos[d], 1);
    edsd[p] = (ushort_t)(s | (d << 8));
  }

  // ---------------- stage x (f32) + GATv2 xl transform -> FEAT (bf16) ----------------
  {
    const float4* x4g = (const float4*)x + (size_t)g * NPG;
    float4* sx4w = (float4*)(SM + O_X);
    if (tid < NPG) sx4w[tid] = x4g[tid];
    const int pl = lane & 31, hb = lane >> 5;
    const float2 wl0 = *(const float2*)&Wl[0*64 + 2*pl];
    const float2 wl1 = *(const float2*)&Wl[1*64 + 2*pl];
    const float2 wl2 = *(const float2*)&Wl[2*64 + 2*pl];
    const float2 wl3 = *(const float2*)&Wl[3*64 + 2*pl];
    const float2 blp = *(const float2*)&bl[2*pl];
    for (int st = 0; st < 16; st++) {
      int i = st*8 + wv*2 + hb;
      float4 xi = x4g[i];
      float l0 = blp.x + xi.x*wl0.x + xi.y*wl1.x + xi.z*wl2.x + xi.w*wl3.x;
      float l1 = blp.y + xi.x*wl0.y + xi.y*wl1.y + xi.z*wl2.y + xi.w*wl3.y;
      sXl[oswz(i, pl)] = pkbf(l0, l1);
    }
  }
  __syncthreads();   // covers CSR scatter + xl + x stage

  // ---------------- GATv2 edge logits: per-dst 8-lane groups, xr on the fly -> f32 lgf ----------------
  {
    const float4* sx4 = (const float4*)(SM + O_X);
    const int grp8 = lane >> 3;
    float4 w0a = *(const float4*)&Wr[0*64 + oc*8], w0b = *(const float4*)&Wr[0*64 + oc*8 + 4];
    float4 w1a = *(const float4*)&Wr[1*64 + oc*8], w1b = *(const float4*)&Wr[1*64 + oc*8 + 4];
    float4 w2a = *(const float4*)&Wr[2*64 + oc*8], w2b = *(const float4*)&Wr[2*64 + oc*8 + 4];
    float4 w3a = *(const float4*)&Wr[3*64 + oc*8], w3b = *(const float4*)&Wr[3*64 + oc*8 + 4];
    float4 bra = *(const float4*)&br[oc*8],  brb = *(const float4*)&br[oc*8 + 4];
    float4 atA = *(const float4*)&att[oc*8], atB = *(const float4*)&att[oc*8 + 4];
    for (int it = 0; it < 4; it++) {
      int d = it*32 + wv*8 + grp8;
      float4 xd = sx4[d];
      float4 xra, xrb;
      xra.x = bra.x + xd.x*w0a.x + xd.y*w1a.x + xd.z*w2a.x + xd.w*w3a.x;
      xra.y = bra.y + xd.x*w0a.y + xd.y*w1a.y + xd.z*w2a.y + xd.w*w3a.y;
      xra.z = bra.z + xd.x*w0a.z + xd.y*w1a.z + xd.z*w2a.z + xd.w*w3a.z;
      xra.w = bra.w + xd.x*w0a.w + xd.y*w1a.w + xd.z*w2a.w + xd.w*w3a.w;
      xrb.x = brb.x + xd.x*w0b.x + xd.y*w1b.x + xd.z*w2b.x + xd.w*w3b.x;
      xrb.y = brb.y + xd.x*w0b.y + xd.y*w1b.y + xd.z*w2b.y + xd.w*w3b.y;
      xrb.z = brb.z + xd.x*w0b.z + xd.y*w1b.z + xd.z*w2b.z + xd.w*w3b.z;
      xrb.w = brb.w + xd.x*w0b.w + xd.y*w1b.w + xd.z*w2b.w + xd.w*w3b.w;
      int p0 = soff[d], p1 = soff[d+1];
      for (int p = p0; p < p1; p++) {
        int s = edsd[p] & 127;
        uint4 ql = *(uint4*)&SM[O_F + obase(s, oc)];
        float e, v;
        v = b2lo(ql.x)+xra.x; e  = lrelu(v,0.2f)*atA.x;
        v = b2hi(ql.x)+xra.y; e += lrelu(v,0.2f)*atA.y;
        v = b2lo(ql.y)+xra.z; e += lrelu(v,0.2f)*atA.z;
        v = b2hi(ql.y)+xra.w; e += lrelu(v,0.2f)*atA.w;
        v = b2lo(ql.z)+xrb.x; e += lrelu(v,0.2f)*atB.x;
        v = b2hi(ql.z)+xrb.y; e += lrelu(v,0.2f)*atB.y;
        v = b2lo(ql.w)+xrb.z; e += lrelu(v,0.2f)*atB.z;
        v = b2hi(ql.w)+xrb.w; e += lrelu(v,0.2f)*atB.w;
        e = DPP_ADD(e, 0x111); e = DPP_ADD(e, 0x112); e = DPP_ADD(e, 0x114);
        if (oc == 7) lgf[p] = e;
      }
    }
  }
  __syncthreads();

  // ---------------- GATv2 softmax (no self): f32 logits -> f16 exp + 1/sum ----------------
  {
    const int g16 = tid >> 4, sl = tid & 15;
    for (int it = 0; it < 8; it++) {
      int d = it*16 + g16;
      int p0 = soff[d], p1 = soff[d+1];
      float m = -1e30f;
      for (int p = p0 + sl; p < p1; p += 16) m = fmaxf(m, lgf[p]);
      #pragma unroll
      for (int o = 1; o < 16; o <<= 1) m = fmaxf(m, __shfl_xor(m, o));
      float ssum = 0.f;
      for (int p = p0 + sl; p < p1; p += 16) {
        float ex = __expf(lgf[p] - m); ssum += ex; evh[p] = (_Float16)ex;
      }
      #pragma unroll
      for (int o = 1; o < 16; o <<= 1) ssum += __shfl_xor(ssum, o);
      if (sl == 0) nmv[d] = 1.f / (ssum + 1e-16f);
    }
  }
  __syncthreads();

  // ---------------- GATv2 gather-aggregate (4 thr/row, 2 passes) + bias + lrelu + LayerNorm ----------------
  {
    const int rr = tid >> 2, qf = tid & 3;
    auto doRow = [&](int d, int stage) {
      float acc[16];
      int p0 = soff[d], p1 = soff[d+1];
      float nmv_d = nmv[d];
      #pragma unroll
      for (int i = 0; i < 16; i++) acc[i] = 0.f;
      for (int p = p0; p < p1; p++) {
        int s = edsd[p] & 127;
        float a = nmv_d * (float)evh[p];
        GF16(s, a)
      }
      float s1 = 0.f, s2 = 0.f;
      #pragma unroll
      for (int j = 0; j < 4; j++) {
        float4 bq = *(const float4*)&bv2[qf*16 + j*4];
        float v0 = lrelu(acc[j*4+0] + bq.x, 0.01f);
        float v1 = lrelu(acc[j*4+1] + bq.y, 0.01f);
        float v2 = lrelu(acc[j*4+2] + bq.z, 0.01f);
        float v3 = lrelu(acc[j*4+3] + bq.w, 0.01f);
        acc[j*4+0]=v0; acc[j*4+1]=v1; acc[j*4+2]=v2; acc[j*4+3]=v3;
        s1 += v0+v1+v2+v3;
        s2 += v0*v0+v1*v1+v2*v2+v3*v3;
      }
      s1 += __shfl_xor(s1, 1); s2 += __shfl_xor(s2, 1);
      s1 += __shfl_xor(s1, 2); s2 += __shfl_xor(s2, 2);
      float mu  = s1 * 0.015625f;
      float var = s2 * 0.015625f - mu*mu;
      float rs  = rsqrtf(var + 1e-5f);
      #pragma unroll
      for (int j = 0; j < 4; j++) {
        float4 gq = *(const float4*)&lng[qf*16 + j*4];
        float4 bq = *(const float4*)&lnb[qf*16 + j*4];
        acc[j*4+0] = (acc[j*4+0]-mu)*rs*gq.x + bq.x;
        acc[j*4+1] = (acc[j*4+1]-mu)*rs*gq.y + bq.y;
        acc[j*4+2] = (acc[j*4+2]-mu)*rs*gq.z + bq.z;
        acc[j*4+3] = (acc[j*4+3]-mu)*rs*gq.w + bq.w;
      }
      __syncthreads();   // pass0: ordering only; pass1: all FEAT reads done
      if (stage) {
        #pragma unroll
        for (int pp = 0; pp < 8; pp++)
          stg[sstg(d, qf*8 + pp)] = pkbf(acc[2*pp], acc[2*pp+1]);
      } else {
        #pragma unroll
        for (int pp = 0; pp < 8; pp++)
          sXl[oswz(d, qf*8 + pp)] = pkbf(acc[2*pp], acc[2*pp+1]);
      }
    };
    doRow(rr, 1);
    doRow(64 + rr, 0);
    #pragma unroll
    for (int i = 0; i < 8; i++) {
      int idx = tid + i*256; int r = idx >> 5, c = idx & 31;
      sXl[oswz(r, c)] = stg[sstg(r, c)];
    }
  }
  __syncthreads();

  // ---------------- two GATConv layers ----------------
  for (int layer = 0; layer < 2; layer++) {
    const float* Wg  = layer ? Wg2 : Wg1;
    const float* avs = layer ? as2 : as1;
    const float* avd = layer ? ad2 : ad1;
    const float* bg  = layer ? bg2 : bg1;

    // stage: waves 0,1 -> wa_s/wa_d = Wg @ a ; waves 2,3 -> WgT bf16 (O_W)
    if (tid < 128) {
      const float* av = (tid < 64) ? avs : avd;
      float* dst = (tid < 64) ? was : wad;
      int k = tid & 63;
      float acc = 0.f;
      #pragma unroll
      for (int jj = 0; jj < 16; jj++) {
        float4 w = *(const float4*)&Wg[k*64 + jj*4];
        float4 a = *(const float4*)&av[jj*4];
        acc += w.x*a.x + w.y*a.y + w.z*a.z + w.w*a.w;
      }
      dst[k] = acc;
    } else {
      int t2 = tid - 128;
      #pragma unroll
      for (int i = 0; i < 8; i++) {
        int idx = t2 + i*128;
        int k = idx >> 4, j4 = (idx & 15)*4;
        float4 w = *(const float4*)&Wg[k*64 + j4];
        wg16[oswz(j4+0, k>>1)*2 + (k&1)] = bfb(w.x);
        wg16[oswz(j4+1, k>>1)*2 + (k&1)] = bfb(w.y);
        wg16[oswz(j4+2, k>>1)*2 + (k&1)] = bfb(w.z);
        wg16[oswz(j4+3, k>>1)*2 + (k&1)] = bfb(w.w);
      }
    }
    __syncthreads();

    // als/ald = h @ wa  (8-lane groups, DPP reduce)
    {
      float4 ws0 = *(float4*)&was[oc*8], ws1 = *(float4*)&was[oc*8 + 4];
      float4 wd0 = *(float4*)&wad[oc*8], wd1 = *(float4*)&wad[oc*8 + 4];
      for (int ps = 0; ps < 4; ps++) {
        int n = ps*32 + (tid >> 3);
        uint4 qv = *(uint4*)&SM[O_F + obase(n, oc)];
        float f0=b2lo(qv.x), f1=b2hi(qv.x), f2=b2lo(qv.y), f3=b2hi(qv.y);
        float f4=b2lo(qv.z), f5=b2hi(qv.z), f6=b2lo(qv.w), f7=b2hi(qv.w);
        float sa = f0*ws0.x+f1*ws0.y+f2*ws0.z+f3*ws0.w+f4*ws1.x+f5*ws1.y+f6*ws1.z+f7*ws1.w;
        float sd = f0*wd0.x+f1*wd0.y+f2*wd0.z+f3*wd0.w+f4*wd1.x+f5*wd1.y+f6*wd1.z+f7*wd1.w;
        sa = DPP_ADD(sa, 0x111); sa = DPP_ADD(sa, 0x112); sa = DPP_ADD(sa, 0x114);
        sd = DPP_ADD(sd, 0x111); sd = DPP_ADD(sd, 0x112); sd = DPP_ADD(sd, 0x114);
        if ((lane & 7) == 7) { als[n] = sa; ald[n] = sd; }
      }
    }
    __syncthreads();

    // transform in place: Xw = h @ Wg (wave-local rows, MFMA) ; then softmax (independent)
    {
      const int r0 = 32*wv;
      uint4 a00 = *(uint4*)&SM[O_F + obase(r0+lw,    lq  )];
      uint4 a01 = *(uint4*)&SM[O_F + obase(r0+lw,    4+lq)];
      uint4 a10 = *(uint4*)&SM[O_F + obase(r0+16+lw, lq  )];
      uint4 a11 = *(uint4*)&SM[O_F + obase(r0+16+lw, 4+lq)];
      uint4 bfr[4][2];
      #pragma unroll
      for (int nt = 0; nt < 4; nt++) {
        bfr[nt][0] = *(uint4*)&SM[O_W + obase(nt*16+lw, lq  )];
        bfr[nt][1] = *(uint4*)&SM[O_W + obase(nt*16+lw, 4+lq)];
      }
      f32x4 c0[4], c1[4];
      #pragma unroll
      for (int nt = 0; nt < 4; nt++) {
        f32x4 z = {0.f,0.f,0.f,0.f};
        c0[nt] = MFMA16(bcs8(a00), bcs8(bfr[nt][0]), z, 0, 0, 0);
        c0[nt] = MFMA16(bcs8(a01), bcs8(bfr[nt][1]), c0[nt], 0, 0, 0);
        c1[nt] = MFMA16(bcs8(a10), bcs8(bfr[nt][0]), z, 0, 0, 0);
        c1[nt] = MFMA16(bcs8(a11), bcs8(bfr[nt][1]), c1[nt], 0, 0, 0);
      }
      #pragma unroll
      for (int nt = 0; nt < 4; nt++) {
        int col = nt*16 + lw;
        #pragma unroll
        for (int rg = 0; rg < 4; rg++) {
          sH16[oswz(r0 + lq*4 + rg,      col>>1)*2 + (col&1)] = bfb(c0[nt][rg]);
          sH16[oswz(r0 + 16 + lq*4 + rg, col>>1)*2 + (col&1)] = bfb(c1[nt][rg]);
        }
      }
    }
    // softmax incl self-loop; logits from als/ald (uses only als/ald/edsd -> safe to merge)
    {
      const int g16 = tid >> 4, sl = tid & 15;
      for (int it = 0; it < 8; it++) {
        int d = it*16 + g16;
        int p0 = soff[d], p1 = soff[d+1];
        float adv = ald[d];
        float se = lrelu(als[d] + adv, 0.2f);
        float m = se;
        for (int p = p0 + sl; p < p1; p += 16)
          m = fmaxf(m, lrelu(als[edsd[p] & 127] + adv, 0.2f));
        #pragma unroll
        for (int o = 1; o < 16; o <<= 1) m = fmaxf(m, __shfl_xor(m, o));
        float ex0 = __expf(se - m);
        float ssum = 0.f;
        for (int p = p0 + sl; p < p1; p += 16) {
          float ex = __expf(lrelu(als[edsd[p] & 127] + adv, 0.2f) - m);
          ssum += ex; evh[p] = (_Float16)ex;
        }
        #pragma unroll
        for (int o = 1; o < 16; o <<= 1) ssum += __shfl_xor(ssum, o);
        if (sl == 0) { nmv[d] = 1.f / (ssum + ex0 + 1e-16f); sse[d] = ex0; }
      }
    }
    __syncthreads();

    // gather-aggregate (+self) 4 thr/row, 2 passes, bias + relu -> FEAT
    {
      const int rr = tid >> 2, qf = tid & 3;
      auto doRow = [&](int d, int stage) {
        float acc[16];
        int p0 = soff[d], p1 = soff[d+1];
        float nmv_d = nmv[d];
        #pragma unroll
        for (int i = 0; i < 16; i++) acc[i] = 0.f;
        {
          float a0 = sse[d] * nmv_d;   // self-loop
          GF16(d, a0)
        }
        for (int p = p0; p < p1; p++) {
          int s = edsd[p] & 127;
          float a = nmv_d * (float)evh[p];
          GF16(s, a)
        }
        #pragma unroll
        for (int j = 0; j < 4; j++) {
          float4 bq = *(const float4*)&bg[qf*16 + j*4];
          acc[j*4+0] = fmaxf(acc[j*4+0] + bq.x, 0.f);
          acc[j*4+1] = fmaxf(acc[j*4+1] + bq.y, 0.f);
          acc[j*4+2] = fmaxf(acc[j*4+2] + bq.z, 0.f);
          acc[j*4+3] = fmaxf(acc[j*4+3] + bq.w, 0.f);
        }
        __syncthreads();   // pass0: ordering only; pass1: all FEAT reads done
        if (stage) {
          #pragma unroll
          for (int pp = 0; pp < 8; pp++)
            stg[sstg(d, qf*8 + pp)] = pkbf(acc[2*pp], acc[2*pp+1]);
        } else {
          #pragma unroll
          for (int pp = 0; pp < 8; pp++)
            sXl[oswz(d, qf*8 + pp)] = pkbf(acc[2*pp], acc[2*pp+1]);
        }
      };
      doRow(rr, 1);
      doRow(64 + rr, 0);
      #pragma unroll
      for (int i = 0; i < 8; i++) {
        int idx = tid + i*256; int r = idx >> 5, c = idx & 31;
        sXl[oswz(r, c)] = stg[sstg(r, c)];
      }
    }
    __syncthreads();
  }

  // ---------------- write h (bf16 pairs, node-major) ----------------
  {
    uint* hg = hout + (size_t)g * 4096;
    #pragma unroll
    for (int i = 0; i < 16; i++) {
      int idx = tid + i*256;
      hg[idx] = SM[O_F + oswz(idx >> 5, idx & 31)];
    }
  }
}

// ---------------- W1 -> W1T bf16 pair transpose ----------------
__global__ __launch_bounds__(256) void w1_transpose(const float* __restrict__ W1,
                                                    uint* __restrict__ w1t)
{
  __shared__ float sw[64*130];
  const int tid = threadIdx.x;
  const int k0 = blockIdx.x * 64;
  #pragma unroll
  for (int i = 0; i < 8; i++) {
    int idx = tid + i*256;
    int r = idx >> 5, c4 = (idx & 31)*4;
    *(float4*)&sw[r*130 + c4] = *(const float4*)&W1[(size_t)(k0+r)*128 + c4];
  }
  __syncthreads();
  #pragma unroll
  for (int i = 0; i < 16; i++) {
    int idx = tid + i*256;
    int c = idx >> 5, kp = idx & 31;
    w1t[(size_t)c*4096 + (k0>>1) + kp] = pkbf(sw[(2*kp)*130 + c], sw[(2*kp+1)*130 + c]);
  }
}

// ---------------- head GEMM: MFMA, split-K 16 ----------------
__global__ __launch_bounds__(256) void head_gemm(
    const uint* __restrict__ hbuf, const uint* __restrict__ w1t,
    float* __restrict__ partial)
{
  __shared__ uint sAh[2048];   // [64 g][32 pairs]
  __shared__ uint sBh[4096];   // [128 c][32 pairs]
  const int tid = threadIdx.x, lane = tid & 63, wv = tid >> 6;
  const int lw = lane & 15, lq = lane >> 4;
  const int g0 = blockIdx.x * 64;
  const int ks = blockIdx.y;
  f32x4 acc[8];
  #pragma unroll
  for (int i = 0; i < 8; i++) acc[i] = f32x4{0.f,0.f,0.f,0.f};

  for (int ch = 0; ch < 8; ch++) {
    int pb = ks*256 + ch*32;
    #pragma unroll
    for (int i = 0; i < 2; i++) {
      int idx = tid + i*256; int r = idx >> 3, q4 = idx & 7;
      uint4 v = *(const uint4*)&hbuf[(size_t)(g0+r)*4096 + pb + q4*4];
      *(uint4*)&sAh[(r<<5) | ((q4 ^ (r & 7))<<2)] = v;
    }
    #pragma unroll
    for (int i = 0; i < 4; i++) {
      int idx = tid + i*256; int r = idx >> 3, q4 = idx & 7;
      uint4 v = *(const uint4*)&w1t[(size_t)r*4096 + pb + q4*4];
      *(uint4*)&sBh[(r<<5) | ((q4 ^ (r & 7))<<2)] = v;
    }
    __syncthreads();
    int ra = 16*wv + lw;
    s8v a0 = bcs8(*(uint4*)&sAh[obase(ra, lq)]);
    s8v a1 = bcs8(*(uint4*)&sAh[obase(ra, 4+lq)]);
    #pragma unroll
    for (int nt = 0; nt < 8; nt++) {
      int c = nt*16 + lw;
      s8v b0 = bcs8(*(uint4*)&sBh[obase(c, lq)]);
      s8v b1 = bcs8(*(uint4*)&sBh[obase(c, 4+lq)]);
      acc[nt] = MFMA16(a0, b0, acc[nt], 0, 0, 0);
      acc[nt] = MFMA16(a1, b1, acc[nt], 0, 0, 0);
    }
    __syncthreads();
  }
  float* pp = partial + (size_t)ks*131072;
  #pragma unroll
  for (int nt = 0; nt < 8; nt++) {
    int c = nt*16 + lw;
    int r0 = g0 + 16*wv + lq*4;
    #pragma unroll
    for (int rg = 0; rg < 4; rg++)
      pp[(size_t)(r0+rg)*128 + c] = acc[nt][rg];
  }
}

// ---------------- head epilogue ----------------
__global__ __launch_bounds__(64) void head_out(
    const float* __restrict__ partial, const float* __restrict__ b1,
    const float* __restrict__ W2, const float* __restrict__ b2,
    float* __restrict__ out)
{
  const int g = blockIdx.x;
  const int l = threadIdx.x;
  float v0 = b1[l], v1 = b1[64 + l];
  #pragma unroll
  for (int s = 0; s < 16; s++) {
    v0 += partial[(size_t)s*131072 + g*128 + l];
    v1 += partial[(size_t)s*131072 + g*128 + 64 + l];
  }
  float sum = lrelu(v0, 0.01f)*W2[l] + lrelu(v1, 0.01f)*W2[64 + l];
  #pragma unroll
  for (int m = 32; m > 0; m >>= 1) sum += __shfl_xor(sum, m);
  if (l == 0) out[g] = 1.f / (1.f + __expf(-(sum + b2[0])));
}

extern "C" void kernel_launch(void* const* d_in, const int* in_sizes, int n_in,
                              void* d_out, int out_size, void* d_ws, size_t ws_size,
                              hipStream_t stream) {
  const float* x   = (const float*)d_in[0];
  const int*   ei  = (const int*)  d_in[1];
  const float* Wl  = (const float*)d_in[2];
  const float* bl_ = (const float*)d_in[3];
  const float* Wr  = (const float*)d_in[4];
  const float* br_ = (const float*)d_in[5];
  const float* att = (const float*)d_in[6];
  const float* bv2 = (const float*)d_in[7];
  const float* Wg1 = (const float*)d_in[8];
  const float* as1 = (const float*)d_in[9];
  const float* ad1 = (const float*)d_in[10];
  const float* bg1 = (const float*)d_in[11];
  const float* Wg2 = (const float*)d_in[12];
  const float* as2 = (const float*)d_in[13];
  const float* ad2 = (const float*)d_in[14];
  const float* bg2 = (const float*)d_in[15];
  const float* lng = (const float*)d_in[16];
  const float* lnb = (const float*)d_in[17];
  const float* W1  = (const float*)d_in[18];
  const float* b1  = (const float*)d_in[19];
  const float* W2  = (const float*)d_in[20];
  const float* b2  = (const float*)d_in[21];
  float* out = (float*)d_out;

  uint*  hbuf    = (uint*)d_ws;                                      // 16 MB
  float* partial = (float*)((char*)d_ws + (size_t)16*1024*1024);     // 8 MB
  uint*  w1t     = (uint*)((char*)d_ws + (size_t)24*1024*1024);      // 2 MB

  w1_transpose<<<128, 256, 0, stream>>>(W1, w1t);
  gnn_fused<<<NGRAPH, 256, 0, stream>>>(x, ei, Wl, bl_, Wr, br_, att, bv2,
      Wg1, as1, ad1, bg1, Wg2, as2, ad2, bg2, lng, lnb, hbuf);
  head_gemm<<<dim3(16, 16), 256, 0, stream>>>(hbuf, w1t, partial);
  head_out<<<NGRAPH, 64, 0, stream>>>(partial, b1, W2, b2, out);
}

// Round 4
// 256.741 us; speedup vs baseline: 1.0488x; 1.0488x over previous
//
#include <hip/hip_runtime.h>
#include <hip/hip_bf16.h>

#define NGRAPH 1024
#define NPG 128
#define NTOT (NGRAPH*NPG)
#define EPG 2048
#define ETOT (NTOT*16)
#define HD 64

typedef unsigned int uint;
typedef unsigned short ushort_t;
typedef __attribute__((ext_vector_type(8))) short s8v;
typedef __attribute__((ext_vector_type(4))) float f32x4;

#define MFMA16 __builtin_amdgcn_mfma_f32_16x16x32_bf16

__device__ __forceinline__ float lrelu(float x, float s){ return fmaxf(x, x*s); }
__device__ __forceinline__ float b2lo(uint u){ return __uint_as_float(u << 16); }
__device__ __forceinline__ float b2hi(uint u){ return __uint_as_float(u & 0xFFFF0000u); }
__device__ __forceinline__ uint pkbf(float a, float b){
  union { __hip_bfloat162 h; uint u; } t;
  t.h = __hip_bfloat162{__float2bfloat16(a), __float2bfloat16(b)};
  return t.u;
}
__device__ __forceinline__ ushort_t bfb(float v){
  __hip_bfloat16 h = __float2bfloat16(v);
  union { __hip_bfloat16 h; ushort_t u; } t; t.h = h; return t.u;
}
union U4S8 { uint4 u; s8v s; };
__device__ __forceinline__ s8v bcs8(uint4 u){ U4S8 t; t.u = u; return t.s; }

// DPP add: disabled/invalid source lanes contribute 0 (row_shr 1/2/4 -> sum at lane&7==7)
#define DPP_ADD(v, ctrl) ((v) + __int_as_float(__builtin_amdgcn_update_dpp(0, __float_as_int(v), (ctrl), 0xF, 0xF, false)))

// ROW32: bf16 rows of 64 (32 u32 pairs), octet-XOR swizzle
__device__ __forceinline__ int oswz(int r, int p){ return (r<<5) | ((((p>>2) ^ (r & 7))<<2) | (p & 3)); }
__device__ __forceinline__ int obase(int r, int oc){ return (r<<5) | (((oc) ^ (r & 7))<<2); }

// LDS map (u32 units) -- 38,416 B total => 4 blocks/CU (all 1024 blocks co-resident)
#define O_F   0        // 4096: FEAT [128][32 pairs] bf16 ROW32: xl -> h -> Xw -> h' (in place)
#define O_W   4096     // 2048: WgT ROW32 [64][32] / GATv2 raw f32 logits [2048]
#define O_EV  6144     // 1024: edge exp values f16 [2048]
#define O_ED  7168     // 1024: edsd u16 [2048]
#define O_X   8192     // 512:  x f32 [128][4]
#define O_SOF 8704     // 129
#define O_SPO 8833     // 128
#define O_NMV 8961     // 128
#define O_SSE 9089     // 128
#define O_ALS 9217     // 128
#define O_ALD 9345     // 128 (+3 pad)
#define O_WAS 9476     // 64 (16B aligned)
#define O_WAD 9540     // 64
#define SM_SZ 9604     // 38,416 B

// gather 32 feats (half hf) of row (s) scaled by (a) into named f32x4 c0..c7
// (named vectors + static components: cannot be demoted to scratch wholesale)
#define GF32(s, a) { \
    uint4 q0 = *(uint4*)&SM[O_F + obase((s), 4*hf+0)]; \
    uint4 q1 = *(uint4*)&SM[O_F + obase((s), 4*hf+1)]; \
    uint4 q2 = *(uint4*)&SM[O_F + obase((s), 4*hf+2)]; \
    uint4 q3 = *(uint4*)&SM[O_F + obase((s), 4*hf+3)]; \
    c0.x += (a)*b2lo(q0.x); c0.y += (a)*b2hi(q0.x); c0.z += (a)*b2lo(q0.y); c0.w += (a)*b2hi(q0.y); \
    c1.x += (a)*b2lo(q0.z); c1.y += (a)*b2hi(q0.z); c1.z += (a)*b2lo(q0.w); c1.w += (a)*b2hi(q0.w); \
    c2.x += (a)*b2lo(q1.x); c2.y += (a)*b2hi(q1.x); c2.z += (a)*b2lo(q1.y); c2.w += (a)*b2hi(q1.y); \
    c3.x += (a)*b2lo(q1.z); c3.y += (a)*b2hi(q1.z); c3.z += (a)*b2lo(q1.w); c3.w += (a)*b2hi(q1.w); \
    c4.x += (a)*b2lo(q2.x); c4.y += (a)*b2hi(q2.x); c4.z += (a)*b2lo(q2.y); c4.w += (a)*b2hi(q2.y); \
    c5.x += (a)*b2lo(q2.z); c5.y += (a)*b2hi(q2.z); c5.z += (a)*b2lo(q2.w); c5.w += (a)*b2hi(q2.w); \
    c6.x += (a)*b2lo(q3.x); c6.y += (a)*b2hi(q3.x); c6.z += (a)*b2lo(q3.y); c6.w += (a)*b2hi(q3.y); \
    c7.x += (a)*b2lo(q3.z); c7.y += (a)*b2hi(q3.z); c7.z += (a)*b2lo(q3.w); c7.w += (a)*b2hi(q3.w); }

// store c0..c7 (32 feats, half hf) into FEAT row d as bf16 pairs
#define STF32(d) { \
    sXl[oswz((d), hf*16+ 0)] = pkbf(c0.x, c0.y); sXl[oswz((d), hf*16+ 1)] = pkbf(c0.z, c0.w); \
    sXl[oswz((d), hf*16+ 2)] = pkbf(c1.x, c1.y); sXl[oswz((d), hf*16+ 3)] = pkbf(c1.z, c1.w); \
    sXl[oswz((d), hf*16+ 4)] = pkbf(c2.x, c2.y); sXl[oswz((d), hf*16+ 5)] = pkbf(c2.z, c2.w); \
    sXl[oswz((d), hf*16+ 6)] = pkbf(c3.x, c3.y); sXl[oswz((d), hf*16+ 7)] = pkbf(c3.z, c3.w); \
    sXl[oswz((d), hf*16+ 8)] = pkbf(c4.x, c4.y); sXl[oswz((d), hf*16+ 9)] = pkbf(c4.z, c4.w); \
    sXl[oswz((d), hf*16+10)] = pkbf(c5.x, c5.y); sXl[oswz((d), hf*16+11)] = pkbf(c5.z, c5.w); \
    sXl[oswz((d), hf*16+12)] = pkbf(c6.x, c6.y); sXl[oswz((d), hf*16+13)] = pkbf(c6.z, c6.w); \
    sXl[oswz((d), hf*16+14)] = pkbf(c7.x, c7.y); sXl[oswz((d), hf*16+15)] = pkbf(c7.z, c7.w); }

__global__ void __launch_bounds__(256, 4) gnn_fused(
    const float* __restrict__ x, const int* __restrict__ ei,
    const float* __restrict__ Wl, const float* __restrict__ bl,
    const float* __restrict__ Wr, const float* __restrict__ br,
    const float* __restrict__ att, const float* __restrict__ bv2,
    const float* __restrict__ Wg1, const float* __restrict__ as1,
    const float* __restrict__ ad1, const float* __restrict__ bg1,
    const float* __restrict__ Wg2, const float* __restrict__ as2,
    const float* __restrict__ ad2, const float* __restrict__ bg2,
    const float* __restrict__ lng, const float* __restrict__ lnb,
    uint* __restrict__ hout)
{
  __shared__ uint SM[SM_SZ];
  uint*      sXl  = SM + O_F;
  _Float16*  evh  = (_Float16*)(SM + O_EV);
  ushort_t*  edsd = (ushort_t*)(SM + O_ED);
  int*       soff = (int*)(SM + O_SOF);
  int*       spos = (int*)(SM + O_SPO);
  float*     nmv  = (float*)(SM + O_NMV);
  float*     sse  = (float*)(SM + O_SSE);
  float*     als  = (float*)(SM + O_ALS);
  float*     ald  = (float*)(SM + O_ALD);
  float*     was  = (float*)(SM + O_WAS);
  float*     wad  = (float*)(SM + O_WAD);
  ushort_t*  sH16 = (ushort_t*)(SM + O_F);
  ushort_t*  wg16 = (ushort_t*)(SM + O_W);
  float*     lgf  = (float*)(SM + O_W);

  const int g    = blockIdx.x;
  const int tid  = threadIdx.x;
  const int lane = tid & 63;
  const int wv   = tid >> 6;
  const int lw   = lane & 15;      // MFMA: col/row low
  const int lq   = lane >> 4;      // MFMA: quad
  const int oc   = lane & 7;       // octet within 64-feat row
  const int ebase = g * EPG;

  // ---------------- CSR build ----------------
  if (tid < NPG) spos[tid] = 0;
  __syncthreads();
  for (int e = tid; e < EPG; e += 256)
    atomicAdd(&spos[ei[ETOT + ebase + e] - g*NPG], 1);
  __syncthreads();
  if (wv == 0) {
    int c0 = spos[lane], c1 = spos[lane + 64];
    #pragma unroll
    for (int o = 1; o < 64; o <<= 1) { int t = __shfl_up(c0, o); if (lane >= o) c0 += t; }
    #pragma unroll
    for (int o = 1; o < 64; o <<= 1) { int t = __shfl_up(c1, o); if (lane >= o) c1 += t; }
    int tot0 = __shfl(c0, 63);
    soff[lane + 1]  = c0;
    soff[lane + 65] = c1 + tot0;
    if (lane == 0) soff[0] = 0;
  }
  __syncthreads();
  if (tid < NPG) spos[tid] = soff[tid];
  __syncthreads();
  for (int e = tid; e < EPG; e += 256) {
    int s = ei[ebase + e] - g*NPG;
    int d = ei[ETOT + ebase + e] - g*NPG;
    int p = atomicAdd(&spos[d], 1);
    edsd[p] = (ushort_t)(s | (d << 8));
  }

  // ---------------- stage x (f32) + GATv2 xl transform -> FEAT (bf16) ----------------
  {
    const float4* x4g = (const float4*)x + (size_t)g * NPG;
    float4* sx4w = (float4*)(SM + O_X);
    if (tid < NPG) sx4w[tid] = x4g[tid];
    const int pl = lane & 31, hb = lane >> 5;
    const float2 wl0 = *(const float2*)&Wl[0*64 + 2*pl];
    const float2 wl1 = *(const float2*)&Wl[1*64 + 2*pl];
    const float2 wl2 = *(const float2*)&Wl[2*64 + 2*pl];
    const float2 wl3 = *(const float2*)&Wl[3*64 + 2*pl];
    const float2 blp = *(const float2*)&bl[2*pl];
    for (int st = 0; st < 16; st++) {
      int i = st*8 + wv*2 + hb;
      float4 xi = x4g[i];
      float l0 = blp.x + xi.x*wl0.x + xi.y*wl1.x + xi.z*wl2.x + xi.w*wl3.x;
      float l1 = blp.y + xi.x*wl0.y + xi.y*wl1.y + xi.z*wl2.y + xi.w*wl3.y;
      sXl[oswz(i, pl)] = pkbf(l0, l1);
    }
  }
  __syncthreads();   // covers CSR scatter + xl + x stage

  // ---------------- GATv2 edge logits: per-dst 8-lane groups, xr on the fly -> f32 lgf ----------------
  {
    const float4* sx4 = (const float4*)(SM + O_X);
    const int grp8 = lane >> 3;
    float4 w0a = *(const float4*)&Wr[0*64 + oc*8], w0b = *(const float4*)&Wr[0*64 + oc*8 + 4];
    float4 w1a = *(const float4*)&Wr[1*64 + oc*8], w1b = *(const float4*)&Wr[1*64 + oc*8 + 4];
    float4 w2a = *(const float4*)&Wr[2*64 + oc*8], w2b = *(const float4*)&Wr[2*64 + oc*8 + 4];
    float4 w3a = *(const float4*)&Wr[3*64 + oc*8], w3b = *(const float4*)&Wr[3*64 + oc*8 + 4];
    float4 bra = *(const float4*)&br[oc*8],  brb = *(const float4*)&br[oc*8 + 4];
    float4 atA = *(const float4*)&att[oc*8], atB = *(const float4*)&att[oc*8 + 4];
    for (int it = 0; it < 4; it++) {
      int d = it*32 + wv*8 + grp8;
      float4 xd = sx4[d];
      float4 xra, xrb;
      xra.x = bra.x + xd.x*w0a.x + xd.y*w1a.x + xd.z*w2a.x + xd.w*w3a.x;
      xra.y = bra.y + xd.x*w0a.y + xd.y*w1a.y + xd.z*w2a.y + xd.w*w3a.y;
      xra.z = bra.z + xd.x*w0a.z + xd.y*w1a.z + xd.z*w2a.z + xd.w*w3a.z;
      xra.w = bra.w + xd.x*w0a.w + xd.y*w1a.w + xd.z*w2a.w + xd.w*w3a.w;
      xrb.x = brb.x + xd.x*w0b.x + xd.y*w1b.x + xd.z*w2b.x + xd.w*w3b.x;
      xrb.y = brb.y + xd.x*w0b.y + xd.y*w1b.y + xd.z*w2b.y + xd.w*w3b.y;
      xrb.z = brb.z + xd.x*w0b.z + xd.y*w1b.z + xd.z*w2b.z + xd.w*w3b.z;
      xrb.w = brb.w + xd.x*w0b.w + xd.y*w1b.w + xd.z*w2b.w + xd.w*w3b.w;
      int p0 = soff[d], p1 = soff[d+1];
      for (int p = p0; p < p1; p++) {
        int s = edsd[p] & 127;
        uint4 ql = *(uint4*)&SM[O_F + obase(s, oc)];
        float e, v;
        v = b2lo(ql.x)+xra.x; e  = lrelu(v,0.2f)*atA.x;
        v = b2hi(ql.x)+xra.y; e += lrelu(v,0.2f)*atA.y;
        v = b2lo(ql.y)+xra.z; e += lrelu(v,0.2f)*atA.z;
        v = b2hi(ql.y)+xra.w; e += lrelu(v,0.2f)*atA.w;
        v = b2lo(ql.z)+xrb.x; e += lrelu(v,0.2f)*atB.x;
        v = b2hi(ql.z)+xrb.y; e += lrelu(v,0.2f)*atB.y;
        v = b2lo(ql.w)+xrb.z; e += lrelu(v,0.2f)*atB.z;
        v = b2hi(ql.w)+xrb.w; e += lrelu(v,0.2f)*atB.w;
        e = DPP_ADD(e, 0x111); e = DPP_ADD(e, 0x112); e = DPP_ADD(e, 0x114);
        if (oc == 7) lgf[p] = e;
      }
    }
  }
  __syncthreads();

  // ---------------- GATv2 softmax (no self): f32 logits -> f16 exp + 1/sum ----------------
  {
    const int g16 = tid >> 4, sl = tid & 15;
    for (int it = 0; it < 8; it++) {
      int d = it*16 + g16;
      int p0 = soff[d], p1 = soff[d+1];
      float m = -1e30f;
      for (int p = p0 + sl; p < p1; p += 16) m = fmaxf(m, lgf[p]);
      #pragma unroll
      for (int o = 1; o < 16; o <<= 1) m = fmaxf(m, __shfl_xor(m, o));
      float ssum = 0.f;
      for (int p = p0 + sl; p < p1; p += 16) {
        float ex = __expf(lgf[p] - m); ssum += ex; evh[p] = (_Float16)ex;
      }
      #pragma unroll
      for (int o = 1; o < 16; o <<= 1) ssum += __shfl_xor(ssum, o);
      if (sl == 0) nmv[d] = 1.f / (ssum + 1e-16f);
    }
  }
  __syncthreads();

  // ---------------- GATv2 gather-aggregate (2 thr/row, named vec accs) + bias + lrelu + LayerNorm ----------------
  {
    const int d = tid >> 1, hf = tid & 1;
    int p0 = soff[d], p1 = soff[d+1];
    float nmv_d = nmv[d];
    f32x4 c0={0,0,0,0}, c1={0,0,0,0}, c2={0,0,0,0}, c3={0,0,0,0};
    f32x4 c4={0,0,0,0}, c5={0,0,0,0}, c6={0,0,0,0}, c7={0,0,0,0};
    for (int p = p0; p < p1; p++) {
      int s = edsd[p] & 127;
      float a = nmv_d * (float)evh[p];
      GF32(s, a)
    }
    float s1 = 0.f, s2 = 0.f;
    #define BRELN(cv, v) { \
      float4 bq = *(const float4*)&bv2[hf*32 + 4*(v)]; \
      cv.x = lrelu(cv.x + bq.x, 0.01f); cv.y = lrelu(cv.y + bq.y, 0.01f); \
      cv.z = lrelu(cv.z + bq.z, 0.01f); cv.w = lrelu(cv.w + bq.w, 0.01f); \
      s1 += cv.x + cv.y + cv.z + cv.w; \
      s2 += cv.x*cv.x + cv.y*cv.y + cv.z*cv.z + cv.w*cv.w; }
    BRELN(c0,0) BRELN(c1,1) BRELN(c2,2) BRELN(c3,3)
    BRELN(c4,4) BRELN(c5,5) BRELN(c6,6) BRELN(c7,7)
    #undef BRELN
    s1 += __shfl_xor(s1, 1); s2 += __shfl_xor(s2, 1);
    float mu  = s1 * 0.015625f;
    float var = s2 * 0.015625f - mu*mu;
    float rs  = rsqrtf(var + 1e-5f);
    #define LNAP(cv, v) { \
      float4 gq = *(const float4*)&lng[hf*32 + 4*(v)]; \
      float4 bq = *(const float4*)&lnb[hf*32 + 4*(v)]; \
      cv.x = (cv.x-mu)*rs*gq.x + bq.x; cv.y = (cv.y-mu)*rs*gq.y + bq.y; \
      cv.z = (cv.z-mu)*rs*gq.z + bq.z; cv.w = (cv.w-mu)*rs*gq.w + bq.w; }
    LNAP(c0,0) LNAP(c1,1) LNAP(c2,2) LNAP(c3,3)
    LNAP(c4,4) LNAP(c5,5) LNAP(c6,6) LNAP(c7,7)
    #undef LNAP
    __syncthreads();   // all gather reads of xl done
    STF32(d)
  }
  __syncthreads();

  // ---------------- two GATConv layers ----------------
  for (int layer = 0; layer < 2; layer++) {
    const float* Wg  = layer ? Wg2 : Wg1;
    const float* avs = layer ? as2 : as1;
    const float* avd = layer ? ad2 : ad1;
    const float* bg  = layer ? bg2 : bg1;

    // stage: waves 0,1 -> wa_s/wa_d = Wg @ a ; waves 2,3 -> WgT bf16 (O_W)
    if (tid < 128) {
      const float* av = (tid < 64) ? avs : avd;
      float* dst = (tid < 64) ? was : wad;
      int k = tid & 63;
      float acc = 0.f;
      #pragma unroll
      for (int jj = 0; jj < 16; jj++) {
        float4 w = *(const float4*)&Wg[k*64 + jj*4];
        float4 a = *(const float4*)&av[jj*4];
        acc += w.x*a.x + w.y*a.y + w.z*a.z + w.w*a.w;
      }
      dst[k] = acc;
    } else {
      int t2 = tid - 128;
      #pragma unroll
      for (int i = 0; i < 8; i++) {
        int idx = t2 + i*128;
        int k = idx >> 4, j4 = (idx & 15)*4;
        float4 w = *(const float4*)&Wg[k*64 + j4];
        wg16[oswz(j4+0, k>>1)*2 + (k&1)] = bfb(w.x);
        wg16[oswz(j4+1, k>>1)*2 + (k&1)] = bfb(w.y);
        wg16[oswz(j4+2, k>>1)*2 + (k&1)] = bfb(w.z);
        wg16[oswz(j4+3, k>>1)*2 + (k&1)] = bfb(w.w);
      }
    }
    __syncthreads();

    // als/ald = h @ wa  (8-lane groups, DPP reduce)
    {
      float4 ws0 = *(float4*)&was[oc*8], ws1 = *(float4*)&was[oc*8 + 4];
      float4 wd0 = *(float4*)&wad[oc*8], wd1 = *(float4*)&wad[oc*8 + 4];
      for (int ps = 0; ps < 4; ps++) {
        int n = ps*32 + (tid >> 3);
        uint4 qv = *(uint4*)&SM[O_F + obase(n, oc)];
        float f0=b2lo(qv.x), f1=b2hi(qv.x), f2=b2lo(qv.y), f3=b2hi(qv.y);
        float f4=b2lo(qv.z), f5=b2hi(qv.z), f6=b2lo(qv.w), f7=b2hi(qv.w);
        float sa = f0*ws0.x+f1*ws0.y+f2*ws0.z+f3*ws0.w+f4*ws1.x+f5*ws1.y+f6*ws1.z+f7*ws1.w;
        float sd = f0*wd0.x+f1*wd0.y+f2*wd0.z+f3*wd0.w+f4*wd1.x+f5*wd1.y+f6*wd1.z+f7*wd1.w;
        sa = DPP_ADD(sa, 0x111); sa = DPP_ADD(sa, 0x112); sa = DPP_ADD(sa, 0x114);
        sd = DPP_ADD(sd, 0x111); sd = DPP_ADD(sd, 0x112); sd = DPP_ADD(sd, 0x114);
        if ((lane & 7) == 7) { als[n] = sa; ald[n] = sd; }
      }
    }
    __syncthreads();

    // transform in place: Xw = h @ Wg (wave-local rows, MFMA) ; then softmax (independent)
    {
      const int r0 = 32*wv;
      uint4 a00 = *(uint4*)&SM[O_F + obase(r0+lw,    lq  )];
      uint4 a01 = *(uint4*)&SM[O_F + obase(r0+lw,    4+lq)];
      uint4 a10 = *(uint4*)&SM[O_F + obase(r0+16+lw, lq  )];
      uint4 a11 = *(uint4*)&SM[O_F + obase(r0+16+lw, 4+lq)];
      uint4 bfr[4][2];
      #pragma unroll
      for (int nt = 0; nt < 4; nt++) {
        bfr[nt][0] = *(uint4*)&SM[O_W + obase(nt*16+lw, lq  )];
        bfr[nt][1] = *(uint4*)&SM[O_W + obase(nt*16+lw, 4+lq)];
      }
      f32x4 c0[4], c1[4];
      #pragma unroll
      for (int nt = 0; nt < 4; nt++) {
        f32x4 z = {0.f,0.f,0.f,0.f};
        c0[nt] = MFMA16(bcs8(a00), bcs8(bfr[nt][0]), z, 0, 0, 0);
        c0[nt] = MFMA16(bcs8(a01), bcs8(bfr[nt][1]), c0[nt], 0, 0, 0);
        c1[nt] = MFMA16(bcs8(a10), bcs8(bfr[nt][0]), z, 0, 0, 0);
        c1[nt] = MFMA16(bcs8(a11), bcs8(bfr[nt][1]), c1[nt], 0, 0, 0);
      }
      #pragma unroll
      for (int nt = 0; nt < 4; nt++) {
        int col = nt*16 + lw;
        #pragma unroll
        for (int rg = 0; rg < 4; rg++) {
          sH16[oswz(r0 + lq*4 + rg,      col>>1)*2 + (col&1)] = bfb(c0[nt][rg]);
          sH16[oswz(r0 + 16 + lq*4 + rg, col>>1)*2 + (col&1)] = bfb(c1[nt][rg]);
        }
      }
    }
    // softmax incl self-loop; logits from als/ald (uses only als/ald/edsd -> safe to merge)
    {
      const int g16 = tid >> 4, sl = tid & 15;
      for (int it = 0; it < 8; it++) {
        int d = it*16 + g16;
        int p0 = soff[d], p1 = soff[d+1];
        float adv = ald[d];
        float se = lrelu(als[d] + adv, 0.2f);
        float m = se;
        for (int p = p0 + sl; p < p1; p += 16)
          m = fmaxf(m, lrelu(als[edsd[p] & 127] + adv, 0.2f));
        #pragma unroll
        for (int o = 1; o < 16; o <<= 1) m = fmaxf(m, __shfl_xor(m, o));
        float ex0 = __expf(se - m);
        float ssum = 0.f;
        for (int p = p0 + sl; p < p1; p += 16) {
          float ex = __expf(lrelu(als[edsd[p] & 127] + adv, 0.2f) - m);
          ssum += ex; evh[p] = (_Float16)ex;
        }
        #pragma unroll
        for (int o = 1; o < 16; o <<= 1) ssum += __shfl_xor(ssum, o);
        if (sl == 0) { nmv[d] = 1.f / (ssum + ex0 + 1e-16f); sse[d] = ex0; }
      }
    }
    __syncthreads();

    // gather-aggregate (+self) 2 thr/row, named vec accs, bias + relu -> FEAT
    {
      const int d = tid >> 1, hf = tid & 1;
      int p0 = soff[d], p1 = soff[d+1];
      float nmv_d = nmv[d];
      f32x4 c0={0,0,0,0}, c1={0,0,0,0}, c2={0,0,0,0}, c3={0,0,0,0};
      f32x4 c4={0,0,0,0}, c5={0,0,0,0}, c6={0,0,0,0}, c7={0,0,0,0};
      {
        float a0 = sse[d] * nmv_d;   // self-loop
        GF32(d, a0)
      }
      for (int p = p0; p < p1; p++) {
        int s = edsd[p] & 127;
        float a = nmv_d * (float)evh[p];
        GF32(s, a)
      }
      #define BREL2(cv, v) { \
        float4 bq = *(const float4*)&bg[hf*32 + 4*(v)]; \
        cv.x = fmaxf(cv.x + bq.x, 0.f); cv.y = fmaxf(cv.y + bq.y, 0.f); \
        cv.z = fmaxf(cv.z + bq.z, 0.f); cv.w = fmaxf(cv.w + bq.w, 0.f); }
      BREL2(c0,0) BREL2(c1,1) BREL2(c2,2) BREL2(c3,3)
      BREL2(c4,4) BREL2(c5,5) BREL2(c6,6) BREL2(c7,7)
      #undef BREL2
      __syncthreads();   // all gather reads of Xw done
      STF32(d)
    }
    __syncthreads();
  }

  // ---------------- write h (bf16 pairs, node-major) ----------------
  {
    uint* hg = hout + (size_t)g * 4096;
    #pragma unroll
    for (int i = 0; i < 16; i++) {
      int idx = tid + i*256;
      hg[idx] = SM[O_F + oswz(idx >> 5, idx & 31)];
    }
  }
}

// ---------------- W1 -> W1T bf16 pair transpose ----------------
__global__ __launch_bounds__(256) void w1_transpose(const float* __restrict__ W1,
                                                    uint* __restrict__ w1t)
{
  __shared__ float sw[64*130];
  const int tid = threadIdx.x;
  const int k0 = blockIdx.x * 64;
  #pragma unroll
  for (int i = 0; i < 8; i++) {
    int idx = tid + i*256;
    int r = idx >> 5, c4 = (idx & 31)*4;
    *(float4*)&sw[r*130 + c4] = *(const float4*)&W1[(size_t)(k0+r)*128 + c4];
  }
  __syncthreads();
  #pragma unroll
  for (int i = 0; i < 16; i++) {
    int idx = tid + i*256;
    int c = idx >> 5, kp = idx & 31;
    w1t[(size_t)c*4096 + (k0>>1) + kp] = pkbf(sw[(2*kp)*130 + c], sw[(2*kp+1)*130 + c]);
  }
}

// ---------------- head GEMM: MFMA, split-K 16 ----------------
__global__ __launch_bounds__(256) void head_gemm(
    const uint* __restrict__ hbuf, const uint* __restrict__ w1t,
    float* __restrict__ partial)
{
  __shared__ uint sAh[2048];   // [64 g][32 pairs]
  __shared__ uint sBh[4096];   // [128 c][32 pairs]
  const int tid = threadIdx.x, lane = tid & 63, wv = tid >> 6;
  const int lw = lane & 15, lq = lane >> 4;
  const int g0 = blockIdx.x * 64;
  const int ks = blockIdx.y;
  f32x4 acc[8];
  #pragma unroll
  for (int i = 0; i < 8; i++) acc[i] = f32x4{0.f,0.f,0.f,0.f};

  for (int ch = 0; ch < 8; ch++) {
    int pb = ks*256 + ch*32;
    #pragma unroll
    for (int i = 0; i < 2; i++) {
      int idx = tid + i*256; int r = idx >> 3, q4 = idx & 7;
      uint4 v = *(const uint4*)&hbuf[(size_t)(g0+r)*4096 + pb + q4*4];
      *(uint4*)&sAh[(r<<5) | ((q4 ^ (r & 7))<<2)] = v;
    }
    #pragma unroll
    for (int i = 0; i < 4; i++) {
      int idx = tid + i*256; int r = idx >> 3, q4 = idx & 7;
      uint4 v = *(const uint4*)&w1t[(size_t)r*4096 + pb + q4*4];
      *(uint4*)&sBh[(r<<5) | ((q4 ^ (r & 7))<<2)] = v;
    }
    __syncthreads();
    int ra = 16*wv + lw;
    s8v a0 = bcs8(*(uint4*)&sAh[obase(ra, lq)]);
    s8v a1 = bcs8(*(uint4*)&sAh[obase(ra, 4+lq)]);
    #pragma unroll
    for (int nt = 0; nt < 8; nt++) {
      int c = nt*16 + lw;
      s8v b0 = bcs8(*(uint4*)&sBh[obase(c, lq)]);
      s8v b1 = bcs8(*(uint4*)&sBh[obase(c, 4+lq)]);
      acc[nt] = MFMA16(a0, b0, acc[nt], 0, 0, 0);
      acc[nt] = MFMA16(a1, b1, acc[nt], 0, 0, 0);
    }
    __syncthreads();
  }
  float* pp = partial + (size_t)ks*131072;
  #pragma unroll
  for (int nt = 0; nt < 8; nt++) {
    int c = nt*16 + lw;
    int r0 = g0 + 16*wv + lq*4;
    #pragma unroll
    for (int rg = 0; rg < 4; rg++)
      pp[(size_t)(r0+rg)*128 + c] = acc[nt][rg];
  }
}

// ---------------- head epilogue ----------------
__global__ __launch_bounds__(64) void head_out(
    const float* __restrict__ partial, const float* __restrict__ b1,
    const float* __restrict__ W2, const float* __restrict__ b2,
    float* __restrict__ out)
{
  const int g = blockIdx.x;
  const int l = threadIdx.x;
  float v0 = b1[l], v1 = b1[64 + l];
  #pragma unroll
  for (int s = 0; s < 16; s++) {
    v0 += partial[(size_t)s*131072 + g*128 + l];
    v1 += partial[(size_t)s*131072 + g*128 + 64 + l];
  }
  float sum = lrelu(v0, 0.01f)*W2[l] + lrelu(v1, 0.01f)*W2[64 + l];
  #pragma unroll
  for (int m = 32; m > 0; m >>= 1) sum += __shfl_xor(sum, m);
  if (l == 0) out[g] = 1.f / (1.f + __expf(-(sum + b2[0])));
}

extern "C" void kernel_launch(void* const* d_in, const int* in_sizes, int n_in,
                              void* d_out, int out_size, void* d_ws, size_t ws_size,
                              hipStream_t stream) {
  const float* x   = (const float*)d_in[0];
  const int*   ei  = (const int*)  d_in[1];
  const float* Wl  = (const float*)d_in[2];
  const float* bl_ = (const float*)d_in[3];
  const float* Wr  = (const float*)d_in[4];
  const float* br_ = (const float*)d_in[5];
  const float* att = (const float*)d_in[6];
  const float* bv2 = (const float*)d_in[7];
  const float* Wg1 = (const float*)d_in[8];
  const float* as1 = (const float*)d_in[9];
  const float* ad1 = (const float*)d_in[10];
  const float* bg1 = (const float*)d_in[11];
  const float* Wg2 = (const float*)d_in[12];
  const float* as2 = (const float*)d_in[13];
  const float* ad2 = (const float*)d_in[14];
  const float* bg2 = (const float*)d_in[15];
  const float* lng = (const float*)d_in[16];
  const float* lnb = (const float*)d_in[17];
  const float* W1  = (const float*)d_in[18];
  const float* b1  = (const float*)d_in[19];
  const float* W2  = (const float*)d_in[20];
  const float* b2  = (const float*)d_in[21];
  float* out = (float*)d_out;

  uint*  hbuf    = (uint*)d_ws;                                      // 16 MB
  float* partial = (float*)((char*)d_ws + (size_t)16*1024*1024);     // 8 MB
  uint*  w1t     = (uint*)((char*)d_ws + (size_t)24*1024*1024);      // 2 MB

  w1_transpose<<<128, 256, 0, stream>>>(W1, w1t);
  gnn_fused<<<NGRAPH, 256, 0, stream>>>(x, ei, Wl, bl_, Wr, br_, att, bv2,
      Wg1, as1, ad1, bg1, Wg2, as2, ad2, bg2, lng, lnb, hbuf);
  head_gemm<<<dim3(16, 16), 256, 0, stream>>>(hbuf, w1t, partial);
  head_out<<<NGRAPH, 64, 0, stream>>>(partial, b1, W2, b2, out);
}